// Round 9
// baseline (199.413 us; speedup 1.0000x reference)
//
#include <hip/hip_runtime.h>
#include <hip/hip_bf16.h>
#include <stdint.h>

// Router: logits = x @ wg^T + gr @ gm^T ; std-normalized softmax; top-2;
// zero expert 7; renormalize. Outputs flat: gates[T,2] | indices[T,2] (as
// float) | logits[T,8].  T=16384, D=2048, E=8.
//
// R9 = R8 split-K + x staged via global_load_lds (direct-to-LDS DMA).
//  Theory: all CU register-load structures plateau at 2.2-2.7 TB/s,
//  consistent with a ~60-line per-CU L1 miss-tracking cap (2.6 TB/s
//  device-wide, wave/prefetch-independent — matches R8 neutrality).
//  global_load_lds bypasses the L1/VGPR return path entirely; if its
//  request tracking is separate, read BW rises. Per wave: private 2x8KB
//  LDS double buffer; 8x1KB loads/batch; manual s_waitcnt vmcnt(8/0)
//  before ds_read_b128 readback (vmcnt retires when the LDS write lands).
//  wg in 32 regs (loaded once), butterfly reduce-scatter, ws + proven
//  epilogue kernel unchanged.

#define DCONST 2048

typedef float f32x4 __attribute__((ext_vector_type(4)));

__device__ __forceinline__ void gload_lds16(const float* g, float* l) {
    __builtin_amdgcn_global_load_lds(
        (const __attribute__((address_space(1))) void*)g,
        (__attribute__((address_space(3))) void*)l, 16, 0, 0);
}

__device__ __forceinline__ unsigned long long shfl_xor_u64(unsigned long long v, int m) {
    int lo = __shfl_xor((int)(uint32_t)v, m, 64);
    int hi = __shfl_xor((int)(uint32_t)(v >> 32), m, 64);
    return ((unsigned long long)(uint32_t)hi << 32) | (unsigned long long)(uint32_t)lo;
}

// ---------------- Kernel 1: split-K partial GEMM ----------------
__global__ __launch_bounds__(256, 2)
void router_gemm(const float* __restrict__ x,   // [T,2048]
                 const float* __restrict__ wg,  // [8,2048]
                 float* __restrict__ ws,        // [T/8][8][64] partials
                 int T)
{
    const int wave = threadIdx.x >> 6;
    const int lane = threadIdx.x & 63;
    const int W    = blockIdx.x * 4 + wave;          // 0..2047

    // per-wave private double buffer: 2 x 8 KB
    __shared__ float lds[4][2][DCONST];              // 64 KB/block
    float* buf0 = &lds[wave][0][0];
    float* buf1 = &lds[wave][1][0];

    const int g     = W & 7;                         // column group (256 cols)
    const int trow0 = (W >> 3) * 32;                 // strip 0; strip 1 = +8192

    // wg slice for this lane's 4 columns, all 8 experts: 32 VGPRs, once.
    const float* wgp = wg + g * 256 + (lane << 2);
    f32x4 w8[8];
    #pragma unroll
    for (int e = 0; e < 8; ++e)
        w8[e] = *(const f32x4*)(wgp + (size_t)e * DCONST);

    #pragma unroll 1
    for (int s = 0; s < 2; ++s) {
        const int trow = trow0 + s * 8192;
        const int tb0  = trow >> 3;
        const float* xp = x + (size_t)trow * DCONST + g * 256 + (lane << 2);

        // issue batch b's 8 rows (1 KB each) into LDS buffer `dst`
        #define LDSLOAD(dst, b)                                               \
            { _Pragma("unroll")                                               \
              for (int i = 0; i < 8; ++i)                                     \
                  gload_lds16(xp + (size_t)((b) * 8 + i) * DCONST,            \
                              dst + i * 256); }

        // read batch back from LDS, 256 fmacs, butterfly, ws partial store
        #define DOBATCH(src, b)                                               \
            { f32x4 r[8];                                                     \
              _Pragma("unroll")                                               \
              for (int i = 0; i < 8; ++i)                                     \
                  r[i] = *(const f32x4*)(src + i * 256 + (lane << 2));        \
              float acc[64];                                                  \
              _Pragma("unroll")                                               \
              for (int v = 0; v < 64; ++v) acc[v] = 0.f;                      \
              _Pragma("unroll")                                               \
              for (int i = 0; i < 8; ++i) {                                   \
                  _Pragma("unroll")                                           \
                  for (int e = 0; e < 8; ++e) {                               \
                      float a = acc[i * 8 + e];                               \
                      a += r[i].x * w8[e].x;                                  \
                      a += r[i].y * w8[e].y;                                  \
                      a += r[i].z * w8[e].z;                                  \
                      a += r[i].w * w8[e].w;                                  \
                      acc[i * 8 + e] = a;                                     \
                  }                                                           \
              }                                                               \
              _Pragma("unroll")                                               \
              for (int m = 1; m < 64; m <<= 1) {                              \
                  const bool up = (lane & m) != 0;                            \
                  _Pragma("unroll")                                           \
                  for (int v = 0; v < 64; v += 2 * m) {                       \
                      const float keep = up ? acc[v + m] : acc[v];            \
                      const float send = up ? acc[v] : acc[v + m];            \
                      const float got  = __shfl_xor(send, m, 64);             \
                      acc[v] = keep + got;                                    \
                  }                                                           \
              }                                                               \
              ws[(size_t)(tb0 + (b)) * 512 + g * 64 + lane] = acc[0]; }

        LDSLOAD(buf0, 0);                       // prologue
        LDSLOAD(buf1, 1);
        __builtin_amdgcn_s_waitcnt(0x0F78);     // vmcnt(8): b0 landed in LDS
        DOBATCH(buf0, 0);
        LDSLOAD(buf0, 2);
        __builtin_amdgcn_s_waitcnt(0x0F78);     // vmcnt(8): b1 landed
        DOBATCH(buf1, 1);
        LDSLOAD(buf1, 3);
        __builtin_amdgcn_s_waitcnt(0x0F78);     // vmcnt(8): b2 landed
        DOBATCH(buf0, 2);
        __builtin_amdgcn_s_waitcnt(0x0F70);     // vmcnt(0): b3 landed
        DOBATCH(buf1, 3);
    }
}

// ---------------- Kernel 2: reduce + epilogue ----------------
__global__ __launch_bounds__(256)
void router_epilogue(const float* __restrict__ ws,  // [T/8][8][64]
                     const float* __restrict__ gm,  // [8,8]
                     const float* __restrict__ gr,  // [T,8]
                     float* __restrict__ out,       // 2T gates | 2T idx | 8T logits
                     int T)
{
    const int wave = threadIdx.x >> 6;
    const int lane = threadIdx.x & 63;
    const int tb   = blockIdx.x * 4 + wave;    // [0, T/8)
    const int t0   = tb * 8;

    float logit = 0.f;
    #pragma unroll
    for (int g = 0; g < 8; ++g)
        logit += ws[(size_t)tb * 512 + g * 64 + lane];

    const int tt = lane >> 3;
    const int f  = lane & 7;
    const int t  = t0 + tt;

    // residual: logit += sum_e gr[t][e] * gm[f][e]
    const float4 ga = *(const float4*)(gr + (size_t)t * 8);
    const float4 gb = *(const float4*)(gr + (size_t)t * 8 + 4);
    const float4 ma = *(const float4*)(gm + f * 8);
    const float4 mb = *(const float4*)(gm + f * 8 + 4);
    logit += ga.x * ma.x + ga.y * ma.y + ga.z * ma.z + ga.w * ma.w
           + gb.x * mb.x + gb.y * mb.y + gb.z * mb.z + gb.w * mb.w;

    // logits output (offset 4T), contiguous per wave
    out[(size_t)4 * T + (size_t)t0 * 8 + lane] = logit;

    // stats over the 8-lane expert group
    float s = logit;
    s += __shfl_xor(s, 1, 64);
    s += __shfl_xor(s, 2, 64);
    s += __shfl_xor(s, 4, 64);
    const float mean = s * 0.125f;
    float d2 = (logit - mean) * (logit - mean);
    d2 += __shfl_xor(d2, 1, 64);
    d2 += __shfl_xor(d2, 2, 64);
    d2 += __shfl_xor(d2, 4, 64);
    const float stdv = sqrtf(d2 / 7.0f);    // ddof=1

    // top-2 via order-preserving 64-bit keys; ties -> smaller index
    uint32_t ob = __float_as_uint(logit);
    ob = (ob & 0x80000000u) ? ~ob : (ob | 0x80000000u);
    unsigned long long k1 = ((unsigned long long)ob << 8) | (unsigned long long)(7 - f);
    unsigned long long k2 = 0ull;
    #pragma unroll
    for (int m = 1; m <= 4; m <<= 1) {
        const unsigned long long o1 = shfl_xor_u64(k1, m);
        const unsigned long long o2 = shfl_xor_u64(k2, m);
        const unsigned long long hi = k1 > o1 ? k1 : o1;
        const unsigned long long lo = k1 > o1 ? o1 : k1;
        const unsigned long long so = k2 > o2 ? k2 : o2;
        k1 = hi;
        k2 = lo > so ? lo : so;
    }
    const int i1 = 7 - (int)(k1 & 0xFFull);
    const int i2 = 7 - (int)(k2 & 0xFFull);
    uint32_t b1 = (uint32_t)(k1 >> 8), b2 = (uint32_t)(k2 >> 8);
    b1 = (b1 & 0x80000000u) ? (b1 ^ 0x80000000u) : ~b1;
    b2 = (b2 & 0x80000000u) ? (b2 ^ 0x80000000u) : ~b2;
    const float l1 = __uint_as_float(b1);
    const float l2 = __uint_as_float(b2);

    // gates: softmax + zero-expert-7 + renorm collapses to a sigmoid
    float g0, g1;
    if (i1 == 7)      { g0 = 0.f; g1 = 1.f; }
    else if (i2 == 7) { g0 = 1.f; g1 = 0.f; }
    else {
        const float p = 1.0f / (1.0f + __expf(-(l1 - l2) / stdv));
        g0 = p; g1 = 1.0f - p;
    }

    if (f == 0) out[(size_t)2 * t]             = g0;
    if (f == 1) out[(size_t)2 * t + 1]         = g1;
    if (f == 2) out[(size_t)2 * T + 2 * t]     = (float)i1;
    if (f == 3) out[(size_t)2 * T + 2 * t + 1] = (float)i2;
}

extern "C" void kernel_launch(void* const* d_in, const int* in_sizes, int n_in,
                              void* d_out, int out_size, void* d_ws, size_t ws_size,
                              hipStream_t stream) {
    const float* x  = (const float*)d_in[0];
    const float* wg = (const float*)d_in[1];
    const float* gm = (const float*)d_in[2];
    const float* gr = (const float*)d_in[3];
    float* ws = (float*)d_ws;                  // needs T/8*512*4 = 4 MB
    const int T = in_sizes[0] / DCONST;        // 16384

    router_gemm<<<512, 256, 0, stream>>>(x, wg, ws, T);       // 2 blocks/CU exact

    const int epi_blocks = T / 32;                            // 512
    router_epilogue<<<epi_blocks, 256, 0, stream>>>(ws, gm, gr, (float*)d_out, T);
}

// Round 10
// 190.401 us; speedup vs baseline: 1.0473x; 1.0473x over previous
//
#include <hip/hip_runtime.h>
#include <hip/hip_bf16.h>
#include <stdint.h>

// Router: logits = x @ wg^T + gr @ gm^T ; std-normalized softmax; top-2;
// zero expert 7; renormalize. Outputs flat: gates[T,2] | indices[T,2] (as
// float) | logits[T,8].  T=16384, D=2048, E=8.
//
// FINAL (= R7, best measured: 189.5 us total, ~60 us kernel).
//  Nine-round evidence: CU read BW for this pattern pins at 2.2-2.7 TB/s
//  across every occupancy / prefetch-depth / load-type (cached, nt,
//  global_load_lds) / access-shape variant. Non-temporal register loads
//  win. dur_us floor ~= 130 us fixed harness overhead + ~45 us x-read at
//  the ~2.8 TB/s empirical CU-read ceiling + ~8 us epilogue = ~185 us.
//  Kernel 1: split-K; wave owns (column-group of 256 cols, 32 tokens);
//    wg slice in 32 VGPRs loaded once; NO LDS, NO barriers. Per 8-token
//    batch: 8x 1KB nt x-loads (ping-pong), 256 fmacs, 64-value butterfly
//    reduce-scatter, 256B partial store to ws (L2-hot for kernel 2).
//  Kernel 2: lane sums 8 column-group partials, then epilogue (std,
//    top-2 via order-preserving keys, sigmoid-collapsed gates).

#define DCONST 2048
#define TOK_PER_BATCH 8
#define BATCHES 4

typedef float f32x4 __attribute__((ext_vector_type(4)));

__device__ __forceinline__ unsigned long long shfl_xor_u64(unsigned long long v, int m) {
    int lo = __shfl_xor((int)(uint32_t)v, m, 64);
    int hi = __shfl_xor((int)(uint32_t)(v >> 32), m, 64);
    return ((unsigned long long)(uint32_t)hi << 32) | (unsigned long long)(uint32_t)lo;
}

// ---------------- Kernel 1: split-K partial GEMM ----------------
__global__ __launch_bounds__(256, 2)
void router_gemm(const float* __restrict__ x,   // [T,2048]
                 const float* __restrict__ wg,  // [8,2048]
                 float* __restrict__ ws,        // [T/8][8][64] partials
                 int T)
{
    const int wave  = threadIdx.x >> 6;
    const int lane  = threadIdx.x & 63;
    const int W     = blockIdx.x * 4 + wave;
    const int g     = W & 7;                 // column group (256 cols)
    const int tbase = (W >> 3) * 32;         // first of 32 tokens

    // wg slice for this lane's 4 columns, all 8 experts: 32 VGPRs, once.
    const float* wgp = wg + g * 256 + (lane << 2);
    f32x4 w8[8];
    #pragma unroll
    for (int e = 0; e < 8; ++e)
        w8[e] = *(const f32x4*)(wgp + (size_t)e * DCONST);

    const float* xp = x + (size_t)tbase * DCONST + g * 256 + (lane << 2);

    f32x4 xa[4], xb[4];

    #define LOADH(buf, trow)                                                  \
        { _Pragma("unroll")                                                   \
          for (int i = 0; i < 4; ++i)                                         \
              buf[i] = __builtin_nontemporal_load(                            \
                  (const f32x4*)(xp + (size_t)((trow) + i) * DCONST)); }

    #define FMAH(buf, tloc0)                                                  \
        { _Pragma("unroll")                                                   \
          for (int i = 0; i < 4; ++i) {                                       \
              _Pragma("unroll")                                               \
              for (int e = 0; e < 8; ++e) {                                   \
                  float a = acc[((tloc0) + i) * 8 + e];                       \
                  a += buf[i].x * w8[e].x;                                    \
                  a += buf[i].y * w8[e].y;                                    \
                  a += buf[i].z * w8[e].z;                                    \
                  a += buf[i].w * w8[e].w;                                    \
                  acc[((tloc0) + i) * 8 + e] = a;                             \
              }                                                               \
          } }

    LOADH(xa, 0);
    LOADH(xb, 4);

    #pragma unroll 1
    for (int b = 0; b < BATCHES; ++b) {
        float acc[64];
        #pragma unroll
        for (int v = 0; v < 64; ++v) acc[v] = 0.f;

        FMAH(xa, 0);                       // tokens b*8 + 0..3
        if (b < BATCHES - 1) LOADH(xa, (b + 1) * 8);
        FMAH(xb, 4);                       // tokens b*8 + 4..7
        if (b < BATCHES - 1) LOADH(xb, (b + 1) * 8 + 4);

        // butterfly reduce-scatter: lane l ends with value l = tloc*8+e
        #pragma unroll
        for (int m = 1; m < 64; m <<= 1) {
            const bool up = (lane & m) != 0;
            #pragma unroll
            for (int v = 0; v < 64; v += 2 * m) {
                const float keep = up ? acc[v + m] : acc[v];
                const float send = up ? acc[v] : acc[v + m];
                const float got  = __shfl_xor(send, m, 64);
                acc[v] = keep + got;
            }
        }

        const int tb = (tbase + b * TOK_PER_BATCH) >> 3;   // token-batch id
        ws[(size_t)tb * 512 + g * 64 + lane] = acc[0];
    }
}

// ---------------- Kernel 2: reduce + epilogue ----------------
__global__ __launch_bounds__(256)
void router_epilogue(const float* __restrict__ ws,  // [T/8][8][64]
                     const float* __restrict__ gm,  // [8,8]
                     const float* __restrict__ gr,  // [T,8]
                     float* __restrict__ out,       // 2T gates | 2T idx | 8T logits
                     int T)
{
    const int wave = threadIdx.x >> 6;
    const int lane = threadIdx.x & 63;
    const int tb   = blockIdx.x * 4 + wave;    // [0, T/8)
    const int t0   = tb * 8;

    float logit = 0.f;
    #pragma unroll
    for (int g = 0; g < 8; ++g)
        logit += ws[(size_t)tb * 512 + g * 64 + lane];

    const int tt = lane >> 3;
    const int f  = lane & 7;
    const int t  = t0 + tt;

    // residual: logit += sum_e gr[t][e] * gm[f][e]
    const float4 ga = *(const float4*)(gr + (size_t)t * 8);
    const float4 gb = *(const float4*)(gr + (size_t)t * 8 + 4);
    const float4 ma = *(const float4*)(gm + f * 8);
    const float4 mb = *(const float4*)(gm + f * 8 + 4);
    logit += ga.x * ma.x + ga.y * ma.y + ga.z * ma.z + ga.w * ma.w
           + gb.x * mb.x + gb.y * mb.y + gb.z * mb.z + gb.w * mb.w;

    // logits output (offset 4T), contiguous per wave
    out[(size_t)4 * T + (size_t)t0 * 8 + lane] = logit;

    // stats over the 8-lane expert group
    float s = logit;
    s += __shfl_xor(s, 1, 64);
    s += __shfl_xor(s, 2, 64);
    s += __shfl_xor(s, 4, 64);
    const float mean = s * 0.125f;
    float d2 = (logit - mean) * (logit - mean);
    d2 += __shfl_xor(d2, 1, 64);
    d2 += __shfl_xor(d2, 2, 64);
    d2 += __shfl_xor(d2, 4, 64);
    const float stdv = sqrtf(d2 / 7.0f);    // ddof=1

    // top-2 via order-preserving 64-bit keys; ties -> smaller index
    uint32_t ob = __float_as_uint(logit);
    ob = (ob & 0x80000000u) ? ~ob : (ob | 0x80000000u);
    unsigned long long k1 = ((unsigned long long)ob << 8) | (unsigned long long)(7 - f);
    unsigned long long k2 = 0ull;
    #pragma unroll
    for (int m = 1; m <= 4; m <<= 1) {
        const unsigned long long o1 = shfl_xor_u64(k1, m);
        const unsigned long long o2 = shfl_xor_u64(k2, m);
        const unsigned long long hi = k1 > o1 ? k1 : o1;
        const unsigned long long lo = k1 > o1 ? o1 : k1;
        const unsigned long long so = k2 > o2 ? k2 : o2;
        k1 = hi;
        k2 = lo > so ? lo : so;
    }
    const int i1 = 7 - (int)(k1 & 0xFFull);
    const int i2 = 7 - (int)(k2 & 0xFFull);
    uint32_t b1 = (uint32_t)(k1 >> 8), b2 = (uint32_t)(k2 >> 8);
    b1 = (b1 & 0x80000000u) ? (b1 ^ 0x80000000u) : ~b1;
    b2 = (b2 & 0x80000000u) ? (b2 ^ 0x80000000u) : ~b2;
    const float l1 = __uint_as_float(b1);
    const float l2 = __uint_as_float(b2);

    // gates: softmax + zero-expert-7 + renorm collapses to a sigmoid
    float g0, g1;
    if (i1 == 7)      { g0 = 0.f; g1 = 1.f; }
    else if (i2 == 7) { g0 = 1.f; g1 = 0.f; }
    else {
        const float p = 1.0f / (1.0f + __expf(-(l1 - l2) / stdv));
        g0 = p; g1 = 1.0f - p;
    }

    if (f == 0) out[(size_t)2 * t]             = g0;
    if (f == 1) out[(size_t)2 * t + 1]         = g1;
    if (f == 2) out[(size_t)2 * T + 2 * t]     = (float)i1;
    if (f == 3) out[(size_t)2 * T + 2 * t + 1] = (float)i2;
}

extern "C" void kernel_launch(void* const* d_in, const int* in_sizes, int n_in,
                              void* d_out, int out_size, void* d_ws, size_t ws_size,
                              hipStream_t stream) {
    const float* x  = (const float*)d_in[0];
    const float* wg = (const float*)d_in[1];
    const float* gm = (const float*)d_in[2];
    const float* gr = (const float*)d_in[3];
    float* ws = (float*)d_ws;                  // needs T/8*512*4 = 4 MB
    const int T = in_sizes[0] / DCONST;        // 16384

    const int gemm_blocks = (8 * (T / 32)) / 4;   // 1024
    router_gemm<<<gemm_blocks, 256, 0, stream>>>(x, wg, ws, T);

    const int epi_blocks = T / 32;                // 512
    router_epilogue<<<epi_blocks, 256, 0, stream>>>(ws, gm, gr, (float*)d_out, T);
}